// Round 15
// baseline (94.797 us; speedup 1.0000x reference)
//
#include <hip/hip_runtime.h>
#include <math.h>

namespace {
constexpr int   NB   = 25;     // basis functions
constexpr int   TS   = 301;    // time steps
constexpr int   NTT  = 19;     // t-tiles of 16 (304)
constexpr float DT   = 0.01f;
constexpr float TAU  = 3.0f;
constexpr float AX   = 2.0f;
constexpr float AZ   = 48.0f;
constexpr float BZ   = 12.0f;  // AZ/4
constexpr int   BATCH = 65536;

typedef float  f32x4  __attribute__((ext_vector_type(4)));
typedef short  s16x8  __attribute__((ext_vector_type(8)));

__device__ inline ushort f2bf(float f) {           // RNE float->bf16
  uint u = __float_as_uint(f);
  uint r = u + 0x7fffu + ((u >> 16) & 1u);
  return (ushort)(r >> 16);
}
__device__ inline float bf2f(ushort h) {
  return __uint_as_float(((uint)h) << 16);
}
}

// ws layout (ushort8 records of 16B):
//   hi table: record[(d*NTT + tt)*64 + lane], 2432 records
//   lo table: follows at +2432 records.                 total 77,824 B
// Record (d,tt,lane): j=0..7 -> B[k = 8*(lane>>4)+j, t = tt*16 + (lane&15)]
//   B[5,t]=A_t, B[6,t]=B_t, B[7+i,t]=H_i[t]*scale[d*27+2+i], else 0.
__global__ __launch_bounds__(512)
void dmp_precompute(const float* __restrict__ c, const float* __restrict__ s2,
                    const float* __restrict__ scale, ushort* __restrict__ ws2) {
  __shared__ float g[TS][NB];
  __shared__ float H[NB + 2][304];
  __shared__ float cS[NB], vS[NB];
  const int tid = threadIdx.x;
  if (tid < NB) { cS[tid] = c[tid]; vS[tid] = s2[tid]; }
  __syncthreads();
  const float q = 1.0f - AX / TAU * DT;   // cx multiplier per step
  for (int i = tid; i < TS; i += 512) {
    float cx = powf(q, (float)(i + 1));   // cx updated BEFORE use in ref
    float p[NB]; float sum = 0.f;
    #pragma unroll
    for (int n = 0; n < NB; ++n) {
      float d = cx - cS[n];
      p[n] = expf(-0.5f * d * d / vS[n]);
      sum += p[n];
    }
    float m = cx / sum;
    #pragma unroll
    for (int n = 0; n < NB; ++n) g[i][n] = p[n] * m;
  }
  __syncthreads();
  if (tid < NB + 2) {
    float y, gl;
    if (tid == 0)      { y = 1.f; gl = 0.f; }   // response to y0
    else if (tid == 1) { y = 0.f; gl = 1.f; }   // response to goal
    else               { y = 0.f; gl = 0.f; }   // response to unit w_n
    float z = 0.f;
    const int nn = (tid >= 2) ? (tid - 2) : 0;
    for (int t = 0; t < TS; ++t) {
      float fx = (tid >= 2) ? g[t][nn] : 0.f;
      float dy = z / TAU;
      float dz = (AZ * (BZ * (gl - y) - z) + fx) / TAU;
      y += dy * DT;
      z += dz * DT;
      H[tid][t] = y;
    }
  }
  __syncthreads();
  // emit bf16 hi/lo B-fragment tables
  constexpr int NREC = 2 * NTT * 64;   // 2432
  for (int rec = tid; rec < NREC; rec += 512) {
    const int d    = rec / (NTT * 64);
    const int rem  = rec - d * (NTT * 64);
    const int tt   = rem >> 6;
    const int lane = rem & 63;
    const int kb   = (lane >> 4) * 8;
    const int t    = tt * 16 + (lane & 15);
    ushort hi8[8], lo8[8];
    #pragma unroll
    for (int j = 0; j < 8; ++j) {
      const int k = kb + j;
      float v = 0.f;
      if (t < TS) {
        if (k == 5)                 v = H[0][t];
        else if (k == 6)            v = H[1][t];
        else if (k >= 7 && k <= 31) v = H[2 + (k - 7)][t] * scale[d * 27 + 2 + (k - 7)];
      }
      const ushort h = f2bf(v);
      hi8[j] = h;
      lo8[j] = f2bf(v - bf2f(h));
    }
    ushort* dst_h = ws2 + (size_t)rec * 8;
    ushort* dst_l = ws2 + (size_t)(NREC + rec) * 8;
    #pragma unroll
    for (int j = 0; j < 8; ++j) { dst_h[j] = hi8[j]; dst_l[j] = lo8[j]; }
  }
}

// GEMM via MFMA (math identical to R14, which validated at absmax 0.031).
// R14 residual cost was store RMW: 64 B segments at row-offset 104 mod 128
// straddle cache lines. Fix: stage the block's 32 out-rows in LDS
// ([32][309]; stride 309 -> ds_writes uniform 2-way = free), then flush
// 9632 CONTIGUOUS floats in dense 512 B chunks (full lines except edges).
// Block = 128 thr = 2 waves = both dofs of 16 batch-pairs.
__global__ __launch_bounds__(128)
void dmp_mfma(const float* __restrict__ x, const float* __restrict__ scale,
              const ushort* __restrict__ ws2, float* __restrict__ out) {
  __shared__ float tile[32][309];
  const int tid  = threadIdx.x;
  const int d    = tid >> 6;                 // wave = dof
  const int lane = tid & 63;
  const int rowb = blockIdx.x * 16;          // 16 batch-pairs per block
  const int m    = lane & 15;
  const int g    = lane >> 4;

  // ---- build A fragment (hi/lo) for rows rowb..rowb+15, this dof ----
  const float* __restrict__ xr = x + (size_t)(2 * (rowb + m) + d) * 27;
  const float vs0 = scale[d * 27], vs1 = scale[d * 27 + 1];
  const float y0s = xr[0] * vs0;
  const float gs  = xr[1] * vs1;
  const float dd  = gs - y0s;
  s16x8 Ah, Al;
  #pragma unroll
  for (int j = 0; j < 8; ++j) {
    const int k   = 8 * g + j;
    const int idx = (k >= 7) ? (k - 5) : 0;      // clamp: no OOB
    const float wv = xr[idx] * dd;
    const float e  = (k < 5) ? 0.f : (k == 5) ? y0s : (k == 6) ? gs : wv;
    const ushort h = f2bf(e);
    Ah[j] = (short)h;
    Al[j] = (short)f2bf(e - bf2f(h));
  }

  constexpr int NREC = 2 * NTT * 64;
  const s16x8* __restrict__ Bh =
      (const s16x8*)ws2 + (size_t)(d * NTT) * 64 + lane;
  const s16x8* __restrict__ Bl = Bh + NREC;

  // D-tile row base in the LDS tile: local out-row = 2*(4g+i) + d
  const int r0 = 8 * g + d;

  #pragma unroll 1
  for (int tt = 0; tt < NTT; ++tt) {
    const s16x8 bh = Bh[tt * 64];
    const s16x8 bl = Bl[tt * 64];
    f32x4 acc = {0.f, 0.f, 0.f, 0.f};
    acc = __builtin_amdgcn_mfma_f32_16x16x32_bf16(Ah, bh, acc, 0, 0, 0);
    acc = __builtin_amdgcn_mfma_f32_16x16x32_bf16(Ah, bl, acc, 0, 0, 0);
    acc = __builtin_amdgcn_mfma_f32_16x16x32_bf16(Al, bh, acc, 0, 0, 0);
    const int col = tt * 16 + m;
    tile[r0 + 0][col] = acc[0];
    tile[r0 + 2][col] = acc[1];
    tile[r0 + 4][col] = acc[2];
    tile[r0 + 6][col] = acc[3];
  }

  __syncthreads();

  // ---- flush: 32 contiguous out-rows = 9632 consecutive floats ----
  float* __restrict__ ob = out + (size_t)(2 * rowb) * TS;
  const float* __restrict__ tl = &tile[0][0];
  constexpr int TOTF = 32 * TS;              // 9632
  #pragma unroll 4
  for (int idx = tid; idx < TOTF; idx += 128) {
    const int r = idx / TS;
    const int c = idx - r * TS;
    ob[idx] = tl[r * 309 + c];
  }
}

extern "C" void kernel_launch(void* const* d_in, const int* in_sizes, int n_in,
                              void* d_out, int out_size, void* d_ws, size_t ws_size,
                              hipStream_t stream) {
  const float* x  = (const float*)d_in[0];
  const float* c  = (const float*)d_in[1];
  const float* s2 = (const float*)d_in[2];
  const float* sc = (const float*)d_in[3];
  ushort* ws2 = (ushort*)d_ws;   // needs 77,824 bytes
  float* out = (float*)d_out;

  hipLaunchKernelGGL(dmp_precompute, dim3(1), dim3(512), 0, stream,
                     c, s2, sc, ws2);
  hipLaunchKernelGGL(dmp_mfma, dim3(BATCH / 16), dim3(128), 0, stream,
                     x, sc, ws2, out);
}

// Round 16
// 78.758 us; speedup vs baseline: 1.2037x; 1.2037x over previous
//
#include <hip/hip_runtime.h>
#include <math.h>

namespace {
constexpr int   NB   = 25;     // basis functions
constexpr int   TS   = 301;    // time steps
constexpr int   NTT  = 19;     // t-tiles of 16 (304)
constexpr float DT   = 0.01f;
constexpr float TAU  = 3.0f;
constexpr float AX   = 2.0f;
constexpr float AZ   = 48.0f;
constexpr float BZ   = 12.0f;  // AZ/4
constexpr int   BATCH = 65536;

typedef float  f32x4  __attribute__((ext_vector_type(4)));
typedef short  s16x8  __attribute__((ext_vector_type(8)));

__device__ inline ushort f2bf(float f) {           // RNE float->bf16
  uint u = __float_as_uint(f);
  uint r = u + 0x7fffu + ((u >> 16) & 1u);
  return (ushort)(r >> 16);
}
__device__ inline float bf2f(ushort h) {
  return __uint_as_float(((uint)h) << 16);
}
}

// ws layout (ushort8 records of 16B):
//   hi table: record[(d*NTT + tt)*64 + lane], 2432 records
//   lo table: follows at +2432 records.                 total 77,824 B
// Record (d,tt,lane): j=0..7 -> B[k = 8*(lane>>4)+j, t = tt*16 + (lane&15)]
//   B[5,t]=A_t, B[6,t]=B_t, B[7+i,t]=H_i[t]*scale[d*27+2+i], else 0.
__global__ __launch_bounds__(512)
void dmp_precompute(const float* __restrict__ c, const float* __restrict__ s2,
                    const float* __restrict__ scale, ushort* __restrict__ ws2) {
  __shared__ float g[TS][NB];
  __shared__ float H[NB + 2][304];
  __shared__ float cS[NB], vS[NB];
  const int tid = threadIdx.x;
  if (tid < NB) { cS[tid] = c[tid]; vS[tid] = s2[tid]; }
  __syncthreads();
  const float q = 1.0f - AX / TAU * DT;   // cx multiplier per step
  for (int i = tid; i < TS; i += 512) {
    float cx = powf(q, (float)(i + 1));   // cx updated BEFORE use in ref
    float p[NB]; float sum = 0.f;
    #pragma unroll
    for (int n = 0; n < NB; ++n) {
      float d = cx - cS[n];
      p[n] = expf(-0.5f * d * d / vS[n]);
      sum += p[n];
    }
    float m = cx / sum;
    #pragma unroll
    for (int n = 0; n < NB; ++n) g[i][n] = p[n] * m;
  }
  __syncthreads();
  if (tid < NB + 2) {
    float y, gl;
    if (tid == 0)      { y = 1.f; gl = 0.f; }   // response to y0
    else if (tid == 1) { y = 0.f; gl = 1.f; }   // response to goal
    else               { y = 0.f; gl = 0.f; }   // response to unit w_n
    float z = 0.f;
    const int nn = (tid >= 2) ? (tid - 2) : 0;
    for (int t = 0; t < TS; ++t) {
      float fx = (tid >= 2) ? g[t][nn] : 0.f;
      float dy = z / TAU;
      float dz = (AZ * (BZ * (gl - y) - z) + fx) / TAU;
      y += dy * DT;
      z += dz * DT;
      H[tid][t] = y;
    }
  }
  __syncthreads();
  constexpr int NREC = 2 * NTT * 64;   // 2432
  for (int rec = tid; rec < NREC; rec += 512) {
    const int d    = rec / (NTT * 64);
    const int rem  = rec - d * (NTT * 64);
    const int tt   = rem >> 6;
    const int lane = rem & 63;
    const int kb   = (lane >> 4) * 8;
    const int t    = tt * 16 + (lane & 15);
    ushort hi8[8], lo8[8];
    #pragma unroll
    for (int j = 0; j < 8; ++j) {
      const int k = kb + j;
      float v = 0.f;
      if (t < TS) {
        if (k == 5)                 v = H[0][t];
        else if (k == 6)            v = H[1][t];
        else if (k >= 7 && k <= 31) v = H[2 + (k - 7)][t] * scale[d * 27 + 2 + (k - 7)];
      }
      const ushort h = f2bf(v);
      hi8[j] = h;
      lo8[j] = f2bf(v - bf2f(h));
    }
    ushort* dst_h = ws2 + (size_t)rec * 8;
    ushort* dst_l = ws2 + (size_t)(NREC + rec) * 8;
    #pragma unroll
    for (int j = 0; j < 8; ++j) { dst_h[j] = hi8[j]; dst_l[j] = lo8[j]; }
  }
}

// MFMA GEMM, R14 math (validated absmax 0.031). Store path reworked:
// block = 256 thr = 4 waves (dof d = w&1, pair-group pg = w>>1) owns 64
// CONTIGUOUS out-rows x all t, processed in 4 t-quarter phases through a
// [64][80] f32 LDS tile (20480 B exactly -> 8 blocks/CU, full residency;
// R15 failure: 39.5 KB tile -> 2 waves/SIMD). Flush writes ~320 B
// contiguous runs; all interior cache lines fully written by this block.
// A-frags built once per block; x read once (FETCH ~14 MB).
__global__ __launch_bounds__(256, 8)
void dmp_mfma(const float* __restrict__ x, const float* __restrict__ scale,
              const ushort* __restrict__ ws2, float* __restrict__ out) {
  __shared__ float tile[64 * 80];
  const int tid  = threadIdx.x;
  const int w    = tid >> 6;
  const int lane = tid & 63;
  const int d    = w & 1;
  const int pg   = w >> 1;
  const int bp   = blockIdx.x;               // 32 batch-pairs per block
  const int m    = lane & 15;
  const int g    = lane >> 4;

  // ---- A fragment (hi/lo) for this wave's 16 rows, built once ----
  const float* __restrict__ xr =
      x + (size_t)(2 * (bp * 32 + pg * 16 + m) + d) * 27;
  const float y0s = xr[0] * scale[d * 27];
  const float gs  = xr[1] * scale[d * 27 + 1];
  const float dd  = gs - y0s;
  s16x8 Ah, Al;
  #pragma unroll
  for (int j = 0; j < 8; ++j) {
    const int k   = 8 * g + j;
    const int idx = (k >= 7) ? (k - 5) : 0;      // clamp: no OOB
    const float wv = xr[idx] * dd;
    const float e  = (k < 5) ? 0.f : (k == 5) ? y0s : (k == 6) ? gs : wv;
    const ushort h = f2bf(e);
    Ah[j] = (short)h;
    Al[j] = (short)f2bf(e - bf2f(h));
  }

  constexpr int NREC = 2 * NTT * 64;
  const s16x8* __restrict__ Bh =
      (const s16x8*)ws2 + (size_t)(d * NTT) * 64 + lane;
  const s16x8* __restrict__ Bl = Bh + NREC;

  // tile row base for this lane's 4 D-values: r = 32pg + 8g + 2i + d
  const int rbase = 32 * pg + 8 * g + d;
  float* __restrict__ ob = out + (size_t)(64 * bp) * TS;

  for (int tq = 0; tq < 4; ++tq) {
    const int tt0 = 5 * tq;
    const int tt1 = (tq == 3) ? NTT : (tt0 + 5);
    for (int tt = tt0; tt < tt1; ++tt) {
      const s16x8 bh = Bh[tt * 64];
      const s16x8 bl = Bl[tt * 64];
      f32x4 acc = {0.f, 0.f, 0.f, 0.f};
      acc = __builtin_amdgcn_mfma_f32_16x16x32_bf16(Ah, bh, acc, 0, 0, 0);
      acc = __builtin_amdgcn_mfma_f32_16x16x32_bf16(Ah, bl, acc, 0, 0, 0);
      acc = __builtin_amdgcn_mfma_f32_16x16x32_bf16(Al, bh, acc, 0, 0, 0);
      const int col = tt * 16 + m - tq * 80;
      float* __restrict__ tp = tile + rbase * 80 + col;
      tp[0]       = acc[0];
      tp[2 * 80]  = acc[1];
      tp[4 * 80]  = acc[2];
      tp[6 * 80]  = acc[3];
    }
    __syncthreads();
    // ---- flush quarter: 64 rows x L valid t, contiguous runs ----
    if (tq < 3) {
      constexpr int L = 80;
      for (int k = 0; k < (64 * L) / 256; ++k) {
        const int idx = k * 256 + tid;
        const int r = idx / L;
        const int c = idx - r * L;
        ob[(size_t)r * TS + tq * 80 + c] = tile[r * 80 + c];
      }
    } else {
      constexpr int L = 61;                  // 301 - 240
      constexpr int TOT = 64 * L;            // 3904
      for (int k = 0; k < 16; ++k) {
        const int idx = k * 256 + tid;
        if (idx < TOT) {
          const int r = idx / L;
          const int c = idx - r * L;
          ob[(size_t)r * TS + 240 + c] = tile[r * 80 + c];
        }
      }
    }
    __syncthreads();
  }
}

extern "C" void kernel_launch(void* const* d_in, const int* in_sizes, int n_in,
                              void* d_out, int out_size, void* d_ws, size_t ws_size,
                              hipStream_t stream) {
  const float* x  = (const float*)d_in[0];
  const float* c  = (const float*)d_in[1];
  const float* s2 = (const float*)d_in[2];
  const float* sc = (const float*)d_in[3];
  ushort* ws2 = (ushort*)d_ws;   // needs 77,824 bytes
  float* out = (float*)d_out;

  hipLaunchKernelGGL(dmp_precompute, dim3(1), dim3(512), 0, stream,
                     c, s2, sc, ws2);
  hipLaunchKernelGGL(dmp_mfma, dim3(BATCH / 32), dim3(256), 0, stream,
                     x, sc, ws2, out);
}

// Round 17
// 76.057 us; speedup vs baseline: 1.2464x; 1.0355x over previous
//
#include <hip/hip_runtime.h>
#include <math.h>

namespace {
constexpr int   NB   = 25;     // basis functions
constexpr int   TS   = 301;    // time steps
constexpr int   NTT  = 19;     // t-tiles of 16 (304)
constexpr float DT   = 0.01f;
constexpr float TAU  = 3.0f;
constexpr float AX   = 2.0f;
constexpr float AZ   = 48.0f;
constexpr float BZ   = 12.0f;  // AZ/4
constexpr int   BATCH = 65536;

typedef float  f32x4  __attribute__((ext_vector_type(4)));
typedef short  s16x8  __attribute__((ext_vector_type(8)));

__device__ inline ushort f2bf(float f) {           // RNE float->bf16
  uint u = __float_as_uint(f);
  uint r = u + 0x7fffu + ((u >> 16) & 1u);
  return (ushort)(r >> 16);
}
__device__ inline float bf2f(ushort h) {
  return __uint_as_float(((uint)h) << 16);
}
}

// ws layout (ushort8 records of 16B):
//   hi table: record[(d*NTT + tt)*64 + lane], 2432 records
//   lo table: follows at +2432 records.                 total 77,824 B
// Record (d,tt,lane): j=0..7 -> B[k = 8*(lane>>4)+j, t = tt*16 + (lane&15)]
//   B[5,t]=A_t, B[6,t]=B_t, B[7+i,t]=H_i[t]*scale[d*27+2+i], else 0.
__global__ __launch_bounds__(512)
void dmp_precompute(const float* __restrict__ c, const float* __restrict__ s2,
                    const float* __restrict__ scale, ushort* __restrict__ ws2) {
  __shared__ float g[TS][NB];
  __shared__ float H[NB + 2][304];
  __shared__ float cS[NB], vS[NB];
  const int tid = threadIdx.x;
  if (tid < NB) { cS[tid] = c[tid]; vS[tid] = s2[tid]; }
  __syncthreads();
  const float q = 1.0f - AX / TAU * DT;   // cx multiplier per step
  for (int i = tid; i < TS; i += 512) {
    float cx = powf(q, (float)(i + 1));   // cx updated BEFORE use in ref
    float p[NB]; float sum = 0.f;
    #pragma unroll
    for (int n = 0; n < NB; ++n) {
      float d = cx - cS[n];
      p[n] = expf(-0.5f * d * d / vS[n]);
      sum += p[n];
    }
    float m = cx / sum;
    #pragma unroll
    for (int n = 0; n < NB; ++n) g[i][n] = p[n] * m;
  }
  __syncthreads();
  if (tid < NB + 2) {
    float y, gl;
    if (tid == 0)      { y = 1.f; gl = 0.f; }   // response to y0
    else if (tid == 1) { y = 0.f; gl = 1.f; }   // response to goal
    else               { y = 0.f; gl = 0.f; }   // response to unit w_n
    float z = 0.f;
    const int nn = (tid >= 2) ? (tid - 2) : 0;
    for (int t = 0; t < TS; ++t) {
      float fx = (tid >= 2) ? g[t][nn] : 0.f;
      float dy = z / TAU;
      float dz = (AZ * (BZ * (gl - y) - z) + fx) / TAU;
      y += dy * DT;
      z += dz * DT;
      H[tid][t] = y;
    }
  }
  __syncthreads();
  constexpr int NREC = 2 * NTT * 64;   // 2432
  for (int rec = tid; rec < NREC; rec += 512) {
    const int d    = rec / (NTT * 64);
    const int rem  = rec - d * (NTT * 64);
    const int tt   = rem >> 6;
    const int lane = rem & 63;
    const int kb   = (lane >> 4) * 8;
    const int t    = tt * 16 + (lane & 15);
    ushort hi8[8], lo8[8];
    #pragma unroll
    for (int j = 0; j < 8; ++j) {
      const int k = kb + j;
      float v = 0.f;
      if (t < TS) {
        if (k == 5)                 v = H[0][t];
        else if (k == 6)            v = H[1][t];
        else if (k >= 7 && k <= 31) v = H[2 + (k - 7)][t] * scale[d * 27 + 2 + (k - 7)];
      }
      const ushort h = f2bf(v);
      hi8[j] = h;
      lo8[j] = f2bf(v - bf2f(h));
    }
    ushort* dst_h = ws2 + (size_t)rec * 8;
    ushort* dst_l = ws2 + (size_t)(NREC + rec) * 8;
    #pragma unroll
    for (int j = 0; j < 8; ++j) { dst_h[j] = hi8[j]; dst_l[j] = lo8[j]; }
  }
}

// MFMA GEMM, R14 math (validated absmax 0.031). Store path: every global
// store instruction is a FULL-LINE 1024 B aligned write (R14/R16 failure:
// 64-320 B misaligned segments -> partial-line store transactions ~2.3TB/s
// effective; harness fill's aligned dwordx4 hits 7 TB/s).
// Block = 256 thr = 4 waves (dof d = w&1, t-half th = w>>1), 32 batch
// pairs, 2 phases of 16 pairs: phase tile [32 out-rows][309] f32 (39.5 KB,
// 4 blocks/CU), flush region 32*1204 B = 38528 B = 301 full cache lines,
// flat float4 flush -> zero partial lines.
__global__ __launch_bounds__(256, 4)
void dmp_mfma(const float* __restrict__ x, const float* __restrict__ scale,
              const ushort* __restrict__ ws2, float* __restrict__ out) {
  __shared__ float tile[32 * 309];
  const int tid  = threadIdx.x;
  const int w    = tid >> 6;
  const int lane = tid & 63;
  const int d    = w & 1;
  const int th   = w >> 1;                   // t-half: tt 0..9 / 10..18
  const int bp   = blockIdx.x;               // 32 batch-pairs per block
  const int m    = lane & 15;
  const int g    = lane >> 4;

  constexpr int NREC = 2 * NTT * 64;
  const s16x8* __restrict__ Bh =
      (const s16x8*)ws2 + (size_t)(d * NTT) * 64 + lane;
  const s16x8* __restrict__ Bl = Bh + NREC;
  const float vs0 = scale[d * 27], vs1 = scale[d * 27 + 1];

  const int tt0 = th ? 10 : 0;
  const int tt1 = th ? NTT : 10;

  for (int p = 0; p < 2; ++p) {
    // ---- A fragment (hi/lo) for this phase's 16 pairs, this dof ----
    const int pair0 = bp * 32 + p * 16;
    const float* __restrict__ xr = x + (size_t)(2 * (pair0 + m) + d) * 27;
    const float y0s = xr[0] * vs0;
    const float gs  = xr[1] * vs1;
    const float dd  = gs - y0s;
    s16x8 Ah, Al;
    #pragma unroll
    for (int j = 0; j < 8; ++j) {
      const int k   = 8 * g + j;
      const int idx = (k >= 7) ? (k - 5) : 0;      // clamp: no OOB
      const float wv = xr[idx] * dd;
      const float e  = (k < 5) ? 0.f : (k == 5) ? y0s : (k == 6) ? gs : wv;
      const ushort h = f2bf(e);
      Ah[j] = (short)h;
      Al[j] = (short)f2bf(e - bf2f(h));
    }

    // tile row for acc[i]: rloc = 2*(4g+i) + d, col = tt*16 + m
    float* __restrict__ tp0 = tile + (size_t)(8 * g + d) * 309 + m;
    for (int tt = tt0; tt < tt1; ++tt) {
      const s16x8 bh = Bh[tt * 64];
      const s16x8 bl = Bl[tt * 64];
      f32x4 acc = {0.f, 0.f, 0.f, 0.f};
      acc = __builtin_amdgcn_mfma_f32_16x16x32_bf16(Ah, bh, acc, 0, 0, 0);
      acc = __builtin_amdgcn_mfma_f32_16x16x32_bf16(Ah, bl, acc, 0, 0, 0);
      acc = __builtin_amdgcn_mfma_f32_16x16x32_bf16(Al, bh, acc, 0, 0, 0);
      float* __restrict__ tp = tp0 + tt * 16;
      tp[0 * 309] = acc[0];
      tp[2 * 309] = acc[1];
      tp[4 * 309] = acc[2];
      tp[6 * 309] = acc[3];
    }
    __syncthreads();

    // ---- flush: 32 contiguous out-rows = 38528 B, 128 B-aligned ----
    // Every wave store = 64 lanes x 16 B = 1024 B contiguous, full lines.
    {
      float4* __restrict__ ob4 =
          (float4*)(out + ((size_t)bp * 64 + p * 32) * TS);
      constexpr int NF4 = 32 * TS / 4;       // 2408
      for (int f = tid; f < NF4; f += 256) {
        const int o = 4 * f;
        float4 v;
        {
          const int r0 = o / TS,       c0 = o - r0 * TS;
          const int r1 = (o + 1) / TS, c1 = (o + 1) - r1 * TS;
          const int r2 = (o + 2) / TS, c2 = (o + 2) - r2 * TS;
          const int r3 = (o + 3) / TS, c3 = (o + 3) - r3 * TS;
          v.x = tile[r0 * 309 + c0];
          v.y = tile[r1 * 309 + c1];
          v.z = tile[r2 * 309 + c2];
          v.w = tile[r3 * 309 + c3];
        }
        ob4[f] = v;
      }
    }
    __syncthreads();
  }
}

extern "C" void kernel_launch(void* const* d_in, const int* in_sizes, int n_in,
                              void* d_out, int out_size, void* d_ws, size_t ws_size,
                              hipStream_t stream) {
  const float* x  = (const float*)d_in[0];
  const float* c  = (const float*)d_in[1];
  const float* s2 = (const float*)d_in[2];
  const float* sc = (const float*)d_in[3];
  ushort* ws2 = (ushort*)d_ws;   // needs 77,824 bytes
  float* out = (float*)d_out;

  hipLaunchKernelGGL(dmp_precompute, dim3(1), dim3(512), 0, stream,
                     c, s2, sc, ws2);
  hipLaunchKernelGGL(dmp_mfma, dim3(BATCH / 32), dim3(256), 0, stream,
                     x, sc, ws2, out);
}